// Round 3
// baseline (67.434 us; speedup 1.0000x reference)
//
#include <hip/hip_runtime.h>

// Chamfer distance, no LDS, no atomics, no memsets, fully deterministic.
// pts = img_render_points[0]      : 4096 x 2 f32 (slice 0)
// refs = ref_catheter_skeleton[1] : 32768 x 2 f32 (last slice; flip is neutral)
//
// ||p-r||^2 = ||p||^2 + (||r||^2 - 2 p.r)
// Staged record per point q: (-2*q.x, -2*q.y, ||q||^2, 0)  -> 16 B
// Inner: d' = fma(px, -2rx, fma(py, -2ry, n2r))  = 2 FMA/pair, min3 amortized.
// Staged reads are block-uniform -> served by scalar/L1 broadcast, LDS pipe idle.

constexpr int N_PTS = 4096;
constexpr int M_REF = 32768;
constexpr int P_OWN = 8;    // own points per thread
constexpr int S_STG = 256;  // staged points per block slice
// rows: 128 ref-slices x 2 own-blocks = 256 blocks (own = pts)
// cols: 16 pt-slices  x 16 own-blocks = 256 blocks (own = refs)

// ---------------- Kernel 0: build staged records ---------------------------
__global__ __launch_bounds__(256) void chamfer_prep_kernel(
    const float2* __restrict__ pts, const float2* __restrict__ refs,
    float4* __restrict__ stg_pts, float4* __restrict__ stg_refs)
{
    const int tid = threadIdx.x, b = blockIdx.x;
    if (b < 16) {
        const int i = b * 256 + tid;
        const float2 p = pts[i];
        stg_pts[i] = make_float4(-2.f * p.x, -2.f * p.y, fmaf(p.x, p.x, p.y * p.y), 0.f);
    } else {
        const int i = (b - 16) * 256 + tid;
        const float2 r = refs[i];
        stg_refs[i] = make_float4(-2.f * r.x, -2.f * r.y, fmaf(r.x, r.x, r.y * r.y), 0.f);
    }
}

// ---------------- Kernel 1: partial mins (each slot written exactly once) --
__global__ __launch_bounds__(256) void chamfer_main_kernel(
    const float2* __restrict__ pts, const float2* __restrict__ refs,
    const float4* __restrict__ stg_pts, const float4* __restrict__ stg_refs,
    float* __restrict__ rowpart,   // [128][N_PTS]
    float* __restrict__ colpart)   // [16][M_REF]
{
    const int tid = threadIdx.x, b = blockIdx.x;

    const float2* own; const float4* stg; float* part;
    int opg, sbase;
    if (b < 256) {                       // rows: own = pts, staged = refs
        const int slice = b >> 1;
        opg   = ((b & 1) << 8) | tid;    // 0..511, 8 pts each
        sbase = slice * S_STG;
        own   = pts;  stg = stg_refs;
        part  = rowpart + slice * N_PTS + opg * P_OWN;
    } else {                             // cols: own = refs, staged = pts
        const int bb = b - 256;
        const int slice = bb >> 4;
        opg   = ((bb & 15) << 8) | tid;  // 0..4095, 8 refs each
        sbase = slice * S_STG;
        own   = refs; stg = stg_pts;
        part  = colpart + slice * M_REF + opg * P_OWN;
    }

    // Load 8 own points (4 x float4 = 64 B contiguous per thread).
    float px[P_OWN], py[P_OWN], mn[P_OWN];
    {
        const float4* o4 = (const float4*)(own + opg * P_OWN);
        #pragma unroll
        for (int q = 0; q < 4; ++q) {
            const float4 o = o4[q];
            px[2 * q] = o.x; py[2 * q] = o.y;
            px[2 * q + 1] = o.z; py[2 * q + 1] = o.w;
        }
        #pragma unroll
        for (int k = 0; k < P_OWN; ++k) mn[k] = 3.0e38f;
    }

    const float4* s = stg + sbase;
    for (int j = 0; j < S_STG; j += 4) {   // block-uniform addresses: broadcast loads
        const float4 r0 = s[j];
        const float4 r1 = s[j + 1];
        const float4 r2 = s[j + 2];
        const float4 r3 = s[j + 3];
        #pragma unroll
        for (int k = 0; k < P_OWN; ++k) {
            const float d0 = fmaf(px[k], r0.x, fmaf(py[k], r0.y, r0.z));
            const float d1 = fmaf(px[k], r1.x, fmaf(py[k], r1.y, r1.z));
            const float d2 = fmaf(px[k], r2.x, fmaf(py[k], r2.y, r2.z));
            const float d3 = fmaf(px[k], r3.x, fmaf(py[k], r3.y, r3.z));
            mn[k] = fminf(fminf(fminf(fminf(mn[k], d0), d1), d2), d3); // 2x v_min3
        }
    }

    // 32 B contiguous store per thread, written exactly once: no init needed.
    float4* w = (float4*)part;
    w[0] = make_float4(mn[0], mn[1], mn[2], mn[3]);
    w[1] = make_float4(mn[4], mn[5], mn[6], mn[7]);
}

// ---------------- Kernel 2: fold slices, add ||own||^2, sqrt, block sums ---
__global__ __launch_bounds__(256) void chamfer_fold_kernel(
    const float4* __restrict__ stg_pts, const float4* __restrict__ stg_refs,
    const float* __restrict__ rowpart, const float* __restrict__ colpart,
    float* __restrict__ blocksum)   // [144]
{
    __shared__ float ssum[4];
    const int tid = threadIdx.x, b = blockIdx.x;
    float d;
    if (b < 16) {
        const int pt = b * 256 + tid;
        float m = 3.0e38f;
        #pragma unroll 8
        for (int sidx = 0; sidx < 128; ++sidx) m = fminf(m, rowpart[sidx * N_PTS + pt]);
        d = sqrtf(fmaxf(m + stg_pts[pt].z, 1e-12f));
    } else {
        const int idx = (b - 16) * 256 + tid;
        float m = 3.0e38f;
        #pragma unroll
        for (int sidx = 0; sidx < 16; ++sidx) m = fminf(m, colpart[sidx * M_REF + idx]);
        d = sqrtf(fmaxf(m + stg_refs[idx].z, 1e-12f));
    }
    #pragma unroll
    for (int off = 32; off > 0; off >>= 1) d += __shfl_down(d, off, 64);
    const int lane = tid & 63, wave = tid >> 6;
    if (lane == 0) ssum[wave] = d;
    __syncthreads();
    if (tid == 0) blocksum[b] = ssum[0] + ssum[1] + ssum[2] + ssum[3];
}

// ---------------- Kernel 3: final sum (plain store) ------------------------
__global__ __launch_bounds__(256) void chamfer_final_kernel(
    const float* __restrict__ blocksum, float* __restrict__ out)
{
    __shared__ float ssum[4];
    const int tid = threadIdx.x;
    float d = (tid < 144) ? blocksum[tid] : 0.f;
    #pragma unroll
    for (int off = 32; off > 0; off >>= 1) d += __shfl_down(d, off, 64);
    const int lane = tid & 63, wave = tid >> 6;
    if (lane == 0) ssum[wave] = d;
    __syncthreads();
    if (tid == 0) out[0] = ssum[0] + ssum[1] + ssum[2] + ssum[3];
}

extern "C" void kernel_launch(void* const* d_in, const int* in_sizes, int n_in,
                              void* d_out, int out_size, void* d_ws, size_t ws_size,
                              hipStream_t stream) {
    const float2* pts  = (const float2*)d_in[0];            // circle 0 (offset 0)
    const float2* refs = ((const float2*)d_in[1]) + M_REF;  // last (=2nd) skeleton slice

    float4* stg_pts  = (float4*)d_ws;                       // 4096  * 16 B =  64 KB
    float4* stg_refs = stg_pts + N_PTS;                     // 32768 * 16 B = 512 KB
    float*  rowpart  = (float*)(stg_refs + M_REF);          // 128*4096 f32 =   2 MB
    float*  colpart  = rowpart + 128 * N_PTS;               //  16*32768 f32 =  2 MB
    float*  blocksum = colpart + 16 * M_REF;                // 144 f32
    float*  out = (float*)d_out;

    chamfer_prep_kernel <<<144, 256, 0, stream>>>(pts, refs, stg_pts, stg_refs);
    chamfer_main_kernel <<<512, 256, 0, stream>>>(pts, refs, stg_pts, stg_refs,
                                                  rowpart, colpart);
    chamfer_fold_kernel <<<144, 256, 0, stream>>>(stg_pts, stg_refs,
                                                  rowpart, colpart, blocksum);
    chamfer_final_kernel<<<1, 256, 0, stream>>>(blocksum, out);
}